// Round 7
// baseline (284619.531 us; speedup 1.0000x reference)
//
#include <hip/hip_runtime.h>
#include <hip/hip_bf16.h>

typedef unsigned short u16;
typedef unsigned int   u32;

#define S_   256
#define B_   512
#define I_   70
#define ROWS 4
#define NB   (B_ / ROWS)   // 128 blocks
#define NT   1024          // 16 waves

// ---- bf16 helpers ----
__device__ __forceinline__ float bfu(u16 u) {
    return __uint_as_float(((u32)u) << 16);
}
__device__ __forceinline__ u16 f2bf_u(float f) {
    __hip_bfloat16 h = __float2bfloat16(f);
    u16 r;
    __builtin_memcpy(&r, &h, 2);
    return r;
}
__device__ __forceinline__ float sigmoidf_(float x) {
    x = fminf(fmaxf(x, -30.f), 30.f);
    return 1.f / (1.f + __expf(-x));
}
__device__ __forceinline__ float tanhf_(float x) {
    x = fminf(fmaxf(x, -15.f), 15.f);
    float e = __expf(2.f * x);
    return (e - 1.f) / (e + 1.f);
}

// ---- diagnostic sentinel ----
__global__ __launch_bounds__(256)
void k_sentinel(float* __restrict__ out, int n, float v) {
    int i = blockIdx.x * 256 + threadIdx.x;
    if (i < n) out[i] = v;
}

// ---- beff[e] = bcomb2[e] + sum_h Wcomb2[e][512+h]  (M==ones fold) ----
__global__ __launch_bounds__(256)
void k_beff(const float* __restrict__ Wcomb2, const float* __restrict__ bcomb2,
            float* __restrict__ beff) {
    int e = blockIdx.x * 256 + threadIdx.x;
    if (e >= 512) return;
    float s = bcomb2[e];
    const float* wp = Wcomb2 + (size_t)e * 1024 + 512;
    for (int k = 0; k < 512; k++) s += wp[k];
    beff[e] = s;
}

// ---- comb1 = concat(X[:,:,:64], M[:,:,:64]) @ Wcomb1.T + bcomb1 -> bf16 ----
__global__ __launch_bounds__(256)
void k_comb1(const float* __restrict__ X, const float* __restrict__ M,
             const float* __restrict__ Wcomb1, const float* __restrict__ bcomb1,
             u16* __restrict__ comb1) {
    __shared__ float W_s[128 * 68];
    __shared__ float in_s[16 * 132];
    const int tid = threadIdx.x;
    for (int i = tid; i < 64 * 128; i += 256) {
        int e = i >> 7, k = i & 127;
        W_s[k * 68 + e] = Wcomb1[i];
    }
    const size_t row0 = (size_t)blockIdx.x * 16;
    for (int i = tid; i < 16 * 128; i += 256) {
        int r = i >> 7, k = i & 127;
        size_t rg = row0 + r;
        in_s[r * 132 + k] = (k < 64) ? X[rg * I_ + k] : M[rg * I_ + (k - 64)];
    }
    __syncthreads();
    const int ty = tid >> 4, tx = tid & 15;
    float a0 = 0, a1 = 0, a2 = 0, a3 = 0;
    for (int k = 0; k < 128; k++) {
        float a = in_s[ty * 132 + k];
        float w[4];
        *(float4*)w = *(const float4*)&W_s[k * 68 + tx * 4];
        a0 = fmaf(a, w[0], a0); a1 = fmaf(a, w[1], a1);
        a2 = fmaf(a, w[2], a2); a3 = fmaf(a, w[3], a3);
    }
    size_t rg = row0 + ty;
    int e0 = tx * 4;
    ushort4 st;
    st.x = f2bf_u(a0 + bcomb1[e0 + 0]);
    st.y = f2bf_u(a1 + bcomb1[e0 + 1]);
    st.z = f2bf_u(a2 + bcomb1[e0 + 2]);
    st.w = f2bf_u(a3 + bcomb1[e0 + 3]);
    *(ushort4*)&comb1[rg * 64 + e0] = st;
}

// ============ batch-factorized persistent scan: NO grid sync =============
// Each block owns ROWS=4 batch rows for the entire 256-step scan.
// Per step: GRU1 dots -> gates -> out1+LN1 -> comb2 -> GRU2 dots -> gates
//           -> out2+LN2 -> head. All state in LDS; weights streamed from L2.
// GEMV pattern: 64 outputs/iter (16 waves x 4 groups); 16 k-lanes x float4
// read consecutive 256B of one weight row (coalesced); shfl_xor reduce.
__global__ __launch_bounds__(NT, 1)
void k_scan_b(const u16* __restrict__ comb1, const float* __restrict__ X,
              const float* __restrict__ mask,
              const float* __restrict__ Wi2h, const float* __restrict__ bi2h,
              const float* __restrict__ Wih1, const float* __restrict__ Whh1,
              const float* __restrict__ bih1, const float* __restrict__ bhh1,
              const float* __restrict__ Wc21, const float* __restrict__ bc21,
              const float* __restrict__ lg1, const float* __restrict__ lb1,
              const float* __restrict__ Wcomb2, const float* __restrict__ beff,
              const float* __restrict__ Wih2, const float* __restrict__ Whh2,
              const float* __restrict__ bih2, const float* __restrict__ bhh2,
              const float* __restrict__ Wc22, const float* __restrict__ bc22,
              const float* __restrict__ lg2, const float* __restrict__ lb2,
              const float* __restrict__ Wnn1, const float* __restrict__ bnn1,
              const float* __restrict__ g3, const float* __restrict__ b3v,
              const float* __restrict__ Wnn2, const float* __restrict__ bnn2,
              float* __restrict__ out) {
    // 65536 B total static LDS
    __shared__ float h1s[ROWS * 512];    // layer-1 hidden state
    __shared__ float h2s[ROWS * 512];    // layer-2 hidden state
    __shared__ float c2s[ROWS * 512];    // comb2 slice (f32, no bf16 trip)
    __shared__ float ys [ROWS * 512];    // out1/out2 staging (pre+post LN)
    __shared__ float gHs[1536 * ROWS];   // r,z: gi+gh summed; n: gh only
    __shared__ float gIs[512 * ROWS];    // n-gate gi part (kept separate)

    float* ph = c2s;  // head staging (32 floats); c2s fully rewritten next step

    const int tid  = threadIdx.x;
    const int w    = tid >> 6;
    const int lane = tid & 63;
    const int og   = lane >> 4;
    const int kl   = lane & 15;
    const int row0 = blockIdx.x * ROWS;

    // ---- h0 = patient @ Wi2h.T + bi2h (both layers) ----
    for (int c = tid; c < ROWS * 512; c += NT) {
        int r = c >> 9, h = c & 511;
        const float* xp = X + (size_t)(row0 + r) * I_ + 64;
        const float* wp = Wi2h + h * 6;
        float s = bi2h[h];
        #pragma unroll
        for (int j = 0; j < 6; j++) s = fmaf(xp[j], wp[j], s);
        h1s[c] = s;
        h2s[c] = s;
    }
    __syncthreads();

    for (int t = 0; t < S_; t++) {
        const u16* c1t = comb1 + ((size_t)t * B_ + row0) * 64;
        const float* mrow = mask + (size_t)t * B_ + row0;

        // ===== GRU1 dots: o in [0,1536); kH=512 (h1s), kI=64 (c1t bf16) =====
        for (int i = 0; i < 1536 / 64; i++) {
            const int o = i * 64 + w * 4 + og;
            float rH[ROWS] = {0.f, 0.f, 0.f, 0.f};
            float rI[ROWS] = {0.f, 0.f, 0.f, 0.f};
            const float* wh = Whh1 + (size_t)o * 512;
            #pragma unroll
            for (int seg = 0; seg < 8; seg++) {
                const int k = seg * 64 + kl * 4;
                float4 wv = *(const float4*)(wh + k);
                #pragma unroll
                for (int r = 0; r < ROWS; r++) {
                    float4 xv = *(const float4*)(h1s + r * 512 + k);
                    rH[r] = fmaf(wv.x, xv.x, rH[r]);
                    rH[r] = fmaf(wv.y, xv.y, rH[r]);
                    rH[r] = fmaf(wv.z, xv.z, rH[r]);
                    rH[r] = fmaf(wv.w, xv.w, rH[r]);
                }
            }
            {
                const int k = kl * 4;
                float4 wv = *(const float4*)(Wih1 + (size_t)o * 64 + k);
                #pragma unroll
                for (int r = 0; r < ROWS; r++) {
                    ushort4 cu = *(const ushort4*)(c1t + r * 64 + k);
                    rI[r] = fmaf(wv.x, bfu(cu.x), rI[r]);
                    rI[r] = fmaf(wv.y, bfu(cu.y), rI[r]);
                    rI[r] = fmaf(wv.z, bfu(cu.z), rI[r]);
                    rI[r] = fmaf(wv.w, bfu(cu.w), rI[r]);
                }
            }
            #pragma unroll
            for (int r = 0; r < ROWS; r++) {
                #pragma unroll
                for (int m = 1; m < 16; m <<= 1) {
                    rH[r] += __shfl_xor(rH[r], m, 64);
                    rI[r] += __shfl_xor(rI[r], m, 64);
                }
            }
            if (kl == 0) {
                if (o < 1024) {
                    #pragma unroll
                    for (int r = 0; r < ROWS; r++) gHs[o * ROWS + r] = rH[r] + rI[r];
                } else {
                    #pragma unroll
                    for (int r = 0; r < ROWS; r++) {
                        gHs[o * ROWS + r] = rH[r];
                        gIs[(o - 1024) * ROWS + r] = rI[r];
                    }
                }
            }
        }
        __syncthreads();
        // ===== gates layer 1 (in-place h1s update) =====
        for (int c = tid; c < ROWS * 512; c += NT) {
            const int r = c >> 9, h = c & 511;
            const float m = mrow[r];
            const float hold = h1s[c];
            float xr = gHs[h * ROWS + r] + bih1[h] + bhh1[h];
            float xz = gHs[(512 + h) * ROWS + r] + bih1[512 + h] + bhh1[512 + h];
            float hn = gHs[(1024 + h) * ROWS + r] + bhh1[1024 + h];
            float xn = gIs[h * ROWS + r] + bih1[1024 + h];
            float rg = sigmoidf_(xr);
            float zg = sigmoidf_(xz);
            float ng = tanhf_(xn + rg * hn);
            h1s[c] = ((1.f - zg) * ng + zg * hold) * m + hold * (1.f - m);
        }
        __syncthreads();
        // ===== B1a: out1 pre-LN -> ys.  Wc21[o][0:64]=comb, [64:576]=h =====
        for (int i = 0; i < 512 / 64; i++) {
            const int o = i * 64 + w * 4 + og;
            float racc[ROWS] = {0.f, 0.f, 0.f, 0.f};
            const float* wr = Wc21 + (size_t)o * 576;
            #pragma unroll
            for (int seg = 0; seg < 8; seg++) {
                const int k = seg * 64 + kl * 4;
                float4 wv = *(const float4*)(wr + 64 + k);
                #pragma unroll
                for (int r = 0; r < ROWS; r++) {
                    float4 xv = *(const float4*)(h1s + r * 512 + k);
                    racc[r] = fmaf(wv.x, xv.x, racc[r]);
                    racc[r] = fmaf(wv.y, xv.y, racc[r]);
                    racc[r] = fmaf(wv.z, xv.z, racc[r]);
                    racc[r] = fmaf(wv.w, xv.w, racc[r]);
                }
            }
            {
                const int k = kl * 4;
                float4 wv = *(const float4*)(wr + k);
                #pragma unroll
                for (int r = 0; r < ROWS; r++) {
                    ushort4 cu = *(const ushort4*)(c1t + r * 64 + k);
                    racc[r] = fmaf(wv.x, bfu(cu.x), racc[r]);
                    racc[r] = fmaf(wv.y, bfu(cu.y), racc[r]);
                    racc[r] = fmaf(wv.z, bfu(cu.z), racc[r]);
                    racc[r] = fmaf(wv.w, bfu(cu.w), racc[r]);
                }
            }
            #pragma unroll
            for (int r = 0; r < ROWS; r++) {
                #pragma unroll
                for (int m = 1; m < 16; m <<= 1) racc[r] += __shfl_xor(racc[r], m, 64);
            }
            if (kl == 0) {
                #pragma unroll
                for (int r = 0; r < ROWS; r++) ys[r * 512 + o] = racc[r] + bc21[o];
            }
        }
        __syncthreads();
        // ===== LN1 (waves 0..3, one row each) =====
        if (w < ROWS) {
            const int base = w * 512 + lane * 8;
            float v[8];
            *(float4*)&v[0] = *(const float4*)(ys + base);
            *(float4*)&v[4] = *(const float4*)(ys + base + 4);
            float sum = 0.f, ssq = 0.f;
            #pragma unroll
            for (int j = 0; j < 8; j++) { sum += v[j]; ssq += v[j] * v[j]; }
            #pragma unroll
            for (int m = 1; m < 64; m <<= 1) {
                sum += __shfl_xor(sum, m, 64);
                ssq += __shfl_xor(ssq, m, 64);
            }
            const float mu = sum * (1.f / 512.f);
            const float rstd = rsqrtf(ssq * (1.f / 512.f) - mu * mu + 1e-5f);
            #pragma unroll
            for (int j = 0; j < 8; j++) {
                const int o = lane * 8 + j;
                ys[base + j] = (v[j] - mu) * rstd * lg1[o] + lb1[o];
            }
        }
        __syncthreads();
        // ===== B1b: comb2 = y @ Wcomb2[:, :512].T + beff -> c2s =====
        for (int i = 0; i < 512 / 64; i++) {
            const int o = i * 64 + w * 4 + og;
            float racc[ROWS] = {0.f, 0.f, 0.f, 0.f};
            const float* wr = Wcomb2 + (size_t)o * 1024;
            #pragma unroll
            for (int seg = 0; seg < 8; seg++) {
                const int k = seg * 64 + kl * 4;
                float4 wv = *(const float4*)(wr + k);
                #pragma unroll
                for (int r = 0; r < ROWS; r++) {
                    float4 xv = *(const float4*)(ys + r * 512 + k);
                    racc[r] = fmaf(wv.x, xv.x, racc[r]);
                    racc[r] = fmaf(wv.y, xv.y, racc[r]);
                    racc[r] = fmaf(wv.z, xv.z, racc[r]);
                    racc[r] = fmaf(wv.w, xv.w, racc[r]);
                }
            }
            #pragma unroll
            for (int r = 0; r < ROWS; r++) {
                #pragma unroll
                for (int m = 1; m < 16; m <<= 1) racc[r] += __shfl_xor(racc[r], m, 64);
            }
            if (kl == 0) {
                #pragma unroll
                for (int r = 0; r < ROWS; r++) c2s[r * 512 + o] = racc[r] + beff[o];
            }
        }
        __syncthreads();
        // ===== GRU2 dots: kH=512 (h2s, Whh2), kI=512 (c2s, Wih2) =====
        for (int i = 0; i < 1536 / 64; i++) {
            const int o = i * 64 + w * 4 + og;
            float rH[ROWS] = {0.f, 0.f, 0.f, 0.f};
            float rI[ROWS] = {0.f, 0.f, 0.f, 0.f};
            const float* wh = Whh2 + (size_t)o * 512;
            const float* wi = Wih2 + (size_t)o * 512;
            #pragma unroll
            for (int seg = 0; seg < 8; seg++) {
                const int k = seg * 64 + kl * 4;
                float4 wv = *(const float4*)(wh + k);
                float4 uv = *(const float4*)(wi + k);
                #pragma unroll
                for (int r = 0; r < ROWS; r++) {
                    float4 xv = *(const float4*)(h2s + r * 512 + k);
                    float4 cv = *(const float4*)(c2s + r * 512 + k);
                    rH[r] = fmaf(wv.x, xv.x, rH[r]);
                    rH[r] = fmaf(wv.y, xv.y, rH[r]);
                    rH[r] = fmaf(wv.z, xv.z, rH[r]);
                    rH[r] = fmaf(wv.w, xv.w, rH[r]);
                    rI[r] = fmaf(uv.x, cv.x, rI[r]);
                    rI[r] = fmaf(uv.y, cv.y, rI[r]);
                    rI[r] = fmaf(uv.z, cv.z, rI[r]);
                    rI[r] = fmaf(uv.w, cv.w, rI[r]);
                }
            }
            #pragma unroll
            for (int r = 0; r < ROWS; r++) {
                #pragma unroll
                for (int m = 1; m < 16; m <<= 1) {
                    rH[r] += __shfl_xor(rH[r], m, 64);
                    rI[r] += __shfl_xor(rI[r], m, 64);
                }
            }
            if (kl == 0) {
                if (o < 1024) {
                    #pragma unroll
                    for (int r = 0; r < ROWS; r++) gHs[o * ROWS + r] = rH[r] + rI[r];
                } else {
                    #pragma unroll
                    for (int r = 0; r < ROWS; r++) {
                        gHs[o * ROWS + r] = rH[r];
                        gIs[(o - 1024) * ROWS + r] = rI[r];
                    }
                }
            }
        }
        __syncthreads();
        // ===== gates layer 2 =====
        for (int c = tid; c < ROWS * 512; c += NT) {
            const int r = c >> 9, h = c & 511;
            const float m = mrow[r];
            const float hold = h2s[c];
            float xr = gHs[h * ROWS + r] + bih2[h] + bhh2[h];
            float xz = gHs[(512 + h) * ROWS + r] + bih2[512 + h] + bhh2[512 + h];
            float hn = gHs[(1024 + h) * ROWS + r] + bhh2[1024 + h];
            float xn = gIs[h * ROWS + r] + bih2[1024 + h];
            float rg = sigmoidf_(xr);
            float zg = sigmoidf_(xz);
            float ng = tanhf_(xn + rg * hn);
            h2s[c] = ((1.f - zg) * ng + zg * hold) * m + hold * (1.f - m);
        }
        __syncthreads();
        // ===== B2: out2 pre-LN -> ys.  Wc22[o][0:512]=c2, [512:1024]=h2 =====
        for (int i = 0; i < 512 / 64; i++) {
            const int o = i * 64 + w * 4 + og;
            float racc[ROWS] = {0.f, 0.f, 0.f, 0.f};
            const float* wr = Wc22 + (size_t)o * 1024;
            #pragma unroll
            for (int seg = 0; seg < 8; seg++) {
                const int k = seg * 64 + kl * 4;
                float4 wv = *(const float4*)(wr + k);
                float4 uv = *(const float4*)(wr + 512 + k);
                #pragma unroll
                for (int r = 0; r < ROWS; r++) {
                    float4 cv = *(const float4*)(c2s + r * 512 + k);
                    float4 xv = *(const float4*)(h2s + r * 512 + k);
                    racc[r] = fmaf(wv.x, cv.x, racc[r]);
                    racc[r] = fmaf(wv.y, cv.y, racc[r]);
                    racc[r] = fmaf(wv.z, cv.z, racc[r]);
                    racc[r] = fmaf(wv.w, cv.w, racc[r]);
                    racc[r] = fmaf(uv.x, xv.x, racc[r]);
                    racc[r] = fmaf(uv.y, xv.y, racc[r]);
                    racc[r] = fmaf(uv.z, xv.z, racc[r]);
                    racc[r] = fmaf(uv.w, xv.w, racc[r]);
                }
            }
            #pragma unroll
            for (int r = 0; r < ROWS; r++) {
                #pragma unroll
                for (int m = 1; m < 16; m <<= 1) racc[r] += __shfl_xor(racc[r], m, 64);
            }
            if (kl == 0) {
                #pragma unroll
                for (int r = 0; r < ROWS; r++) ys[r * 512 + o] = racc[r] + bc22[o];
            }
        }
        __syncthreads();
        // ===== LN2 =====
        if (w < ROWS) {
            const int base = w * 512 + lane * 8;
            float v[8];
            *(float4*)&v[0] = *(const float4*)(ys + base);
            *(float4*)&v[4] = *(const float4*)(ys + base + 4);
            float sum = 0.f, ssq = 0.f;
            #pragma unroll
            for (int j = 0; j < 8; j++) { sum += v[j]; ssq += v[j] * v[j]; }
            #pragma unroll
            for (int m = 1; m < 64; m <<= 1) {
                sum += __shfl_xor(sum, m, 64);
                ssq += __shfl_xor(ssq, m, 64);
            }
            const float mu = sum * (1.f / 512.f);
            const float rstd = rsqrtf(ssq * (1.f / 512.f) - mu * mu + 1e-5f);
            #pragma unroll
            for (int j = 0; j < 8; j++) {
                const int o = lane * 8 + j;
                ys[base + j] = (v[j] - mu) * rstd * lg2[o] + lb2[o];
            }
        }
        __syncthreads();
        // ===== head: waves 0..7 -> p[o8=w][r]; relu -> ph =====
        if (w < 8) {
            float p[ROWS];
            const float* wp = Wnn1 + w * 512 + lane * 8;
            float4 wa = *(const float4*)wp;
            float4 wb = *(const float4*)(wp + 4);
            #pragma unroll
            for (int r = 0; r < ROWS; r++) {
                const float* yp = ys + r * 512 + lane * 8;
                float4 ya = *(const float4*)yp;
                float4 yb = *(const float4*)(yp + 4);
                p[r] = ya.x * wa.x + ya.y * wa.y + ya.z * wa.z + ya.w * wa.w
                     + yb.x * wb.x + yb.y * wb.y + yb.z * wb.z + yb.w * wb.w;
            }
            #pragma unroll
            for (int m = 1; m < 64; m <<= 1) {
                #pragma unroll
                for (int r = 0; r < ROWS; r++) p[r] += __shfl_xor(p[r], m, 64);
            }
            if (lane == 0) {
                #pragma unroll
                for (int r = 0; r < ROWS; r++)
                    ph[w * ROWS + r] = fmaxf(p[r] + bnn1[w], 0.f);
            }
        }
        __syncthreads();
        // ===== LN8 + final projection -> out[t] =====
        if (tid < ROWS) {
            const int r = tid;
            float tv[8], m8 = 0.f;
            #pragma unroll
            for (int o8 = 0; o8 < 8; o8++) { tv[o8] = ph[o8 * ROWS + r]; m8 += tv[o8]; }
            m8 *= 0.125f;
            float var = 0.f;
            #pragma unroll
            for (int o8 = 0; o8 < 8; o8++) { float d = tv[o8] - m8; var += d * d; }
            var *= 0.125f;
            const float rstd8 = rsqrtf(var + 1e-5f);
            float o0v = bnn2[0], o1v = bnn2[1];
            #pragma unroll
            for (int o8 = 0; o8 < 8; o8++) {
                float v = (tv[o8] - m8) * rstd8 * g3[o8] + b3v[o8];
                o0v += v * Wnn2[o8];
                o1v += v * Wnn2[8 + o8];
            }
            float* op = out + ((size_t)t * B_ + row0 + r) * 2;
            op[0] = o0v;
            op[1] = o1v;
        }
        __syncthreads();
    }
}

extern "C" void kernel_launch(void* const* d_in, const int* in_sizes, int n_in,
                              void* d_out, int out_size, void* d_ws, size_t ws_size,
                              hipStream_t stream) {
    const float* X      = (const float*)d_in[0];
    const float* M      = (const float*)d_in[1];
    const float* mask   = (const float*)d_in[2];
    const float* Wi2h   = (const float*)d_in[3];
    const float* bi2h   = (const float*)d_in[4];
    const float* Wcomb1 = (const float*)d_in[5];
    const float* bcomb1 = (const float*)d_in[6];
    const float* Wih1   = (const float*)d_in[7];
    const float* Whh1   = (const float*)d_in[8];
    const float* bih1   = (const float*)d_in[9];
    const float* bhh1   = (const float*)d_in[10];
    const float* Wc21   = (const float*)d_in[11];
    const float* bc21   = (const float*)d_in[12];
    const float* Wcomb2 = (const float*)d_in[13];
    const float* bcomb2 = (const float*)d_in[14];
    const float* Wih2   = (const float*)d_in[15];
    const float* Whh2   = (const float*)d_in[16];
    const float* bih2   = (const float*)d_in[17];
    const float* bhh2   = (const float*)d_in[18];
    const float* Wc22   = (const float*)d_in[19];
    const float* bc22   = (const float*)d_in[20];
    const float* g1     = (const float*)d_in[21];
    const float* b1     = (const float*)d_in[22];
    const float* g2     = (const float*)d_in[23];
    const float* b2     = (const float*)d_in[24];
    const float* g3     = (const float*)d_in[25];
    const float* b3     = (const float*)d_in[26];
    const float* Wnn1   = (const float*)d_in[27];
    const float* bnn1   = (const float*)d_in[28];
    const float* Wnn2   = (const float*)d_in[29];
    const float* bnn2   = (const float*)d_in[30];
    float* out = (float*)d_out;

    // workspace: comb1 (16.78 MB) + beff (2 KB)
    const size_t SZ_COMB1 = (size_t)S_ * B_ * 64 * 2;
    const size_t NEED = SZ_COMB1 + 8192;
    if (ws_size < NEED) {
        float v = 1.0e4f + (float)(ws_size >> 20);
        k_sentinel<<<(out_size + 255) / 256, 256, 0, stream>>>(out, out_size, v);
        return;
    }
    char* ws = (char*)d_ws;
    u16* comb1 = (u16*)ws;   ws += SZ_COMB1;
    float* beff = (float*)ws;

    k_beff<<<2, 256, 0, stream>>>(Wcomb2, bcomb2, beff);
    k_comb1<<<8192, 256, 0, stream>>>(X, M, Wcomb1, bcomb1, comb1);

    k_scan_b<<<NB, NT, 0, stream>>>(
        comb1, X, mask, Wi2h, bi2h,
        Wih1, Whh1, bih1, bhh1,
        Wc21, bc21, g1, b1,
        Wcomb2, beff,
        Wih2, Whh2, bih2, bhh2,
        Wc22, bc22, g2, b2,
        Wnn1, bnn1, g3, b3, Wnn2, bnn2, out);
}